// Round 10
// baseline (115.100 us; speedup 1.0000x reference)
//
#include <hip/hip_runtime.h>
#include <math.h>

#define T_STEPS 730
#define NB      1000
#define LENF    15
#define NEARZ   1e-5f
#define SGW     8000           // plane width: 1000 basins x 8 members
#define NPAIR   365            // 730/2 (Sn,Gn) pairs per lane
#define TT      50             // finalize: t-rows per block (even!)
#define BBLK    32             // finalize: basins per block

// ===========================================================================
// R10 = R9 (113.0us, passing) with ONE change: finalize's row loop issues
// ZERO global stores.  Session law (R0/R7/R9): lone-wave time ~ slots x 7cy
// -> scan is at its ~15-slot floor; left alone (bit-identical).  Finalize
// theory: the 3 scatter dword stores/row (stride-24B, ~24 lines/wave-store)
// share the vmcnt FIFO with the pair-pipeline loads -> every s_waitcnt
// before consuming a prefetched pair retires older scatter stores first
// (same coupling R2->R3 removed on the load side for the scan, worth 10us).
//   (a) ch3..5 row sums -> LDS (ash/ssh/gsh, +19.8KB, 36.7KB total);
//   (b) written coalesced-ish in the post-barrier phase (no loads after);
//   (c) pair pipeline 4 -> 8 deep (covers ~800cy HBM latency).
// ===========================================================================

// ---- PASS A (unchanged from R9) -------------------------------------------
#define DSLD(R, CI)                                                            \
  _Pragma("unroll")                                                            \
  for (int j = 0; j < 8; ++j) R[j] = xs[((CI) * 8 + j) * 8 + bl];              \
  __builtin_amdgcn_sched_barrier(0);

#define CONV(V, R)                                                             \
  _Pragma("unroll")                                                            \
  for (int j = 0; j < 8; ++j)                                                  \
      V[j] = make_float2(R[j].x, __builtin_amdgcn_exp2f(R[j].y * nbl));

#define STEPP(V0, V1)                                                          \
  {                                                                            \
    float W0  = (V0).x + S;                                                    \
    float t0  = fmaf(W0, inv2a, pb2a);                                         \
    float d0  = fmaf(t0, t0, -(W0 * boa));                                     \
    float r0  = __builtin_amdgcn_sqrtf(fmaxf(d0, NEARZ));                      \
    float Y0  = t0 - r0;                                                       \
    float Sn0 = Y0 * (V0).y;                                                   \
    float av0 = W0 - Y0;                                                       \
    float Gn0 = fmaf(pc, av0, G) * i1d;                                        \
    float W1  = (V1).x + Sn0;                                                  \
    float t1  = fmaf(W1, inv2a, pb2a);                                         \
    float d1  = fmaf(t1, t1, -(W1 * boa));                                     \
    float r1  = __builtin_amdgcn_sqrtf(fmaxf(d1, NEARZ));                      \
    float Y1  = t1 - r1;                                                       \
    float Sn1 = Y1 * (V1).y;                                                   \
    float av1 = W1 - Y1;                                                       \
    G = fmaf(pc, av1, Gn0) * i1d;                                              \
    S = Sn1;                                                                   \
    *ps4 = make_float4(Sn0, Gn0, Sn1, G);                                      \
    ps4 += SGW;                                                                \
  }

#define CONS(V) STEPP(V[0], V[1]) STEPP(V[2], V[3])                            \
                STEPP(V[4], V[5]) STEPP(V[6], V[7])

__global__ __launch_bounds__(64, 1) void scan_state(const float* __restrict__ x,
                                                    const float* __restrict__ raw,
                                                    float4* __restrict__ sg4) {
    __shared__ float4 xs4[2944];               // 736 rows x 8 basins x float2
    const float2* xs = (const float2*)xs4;

    const int L   = threadIdx.x;
    const int gid = blockIdx.x * 64 + L;       // 0..7999 (grid=125)
    const int b   = gid >> 3;
    const int m   = gid & 7;
    const int bl  = L >> 3;                    // basin-local 0..7

    // ---- one-time cooperative x -> LDS stage ------------------------------
    {
        float4 tmp[46];
#pragma unroll
        for (int ch = 0; ch < 46; ++ch) {
            int idx = ch * 64 + L;             // 0..2943
            int row = idx >> 2;                // t row 0..735
            row = row < T_STEPS ? row : (T_STEPS - 1);
            tmp[ch] = *(const float4*)((const char*)x + (size_t)row * (NB * 8)
                                       + (size_t)(blockIdx.x * 64)
                                       + (size_t)(idx & 3) * 16);
        }
#pragma unroll
        for (int ch = 0; ch < 46; ++ch) xs4[ch * 64 + L] = tmp[ch];
    }
    __syncthreads();

    // raw layout (B,34) = [a(8), b(8), c(8), d(8), ra, rb]
    const float* rp = raw + b * 34;
    float pa = rp[0 * 8 + m] * 0.9f + 0.1f;
    float pb = rp[1 * 8 + m] * 450.0f + 50.0f;
    float pc = rp[2 * 8 + m];
    float pd = rp[3 * 8 + m] * 0.89f + 0.01f;

    float inv2a = 1.0f / (2.0f * pa);
    float pb2a  = pb * inv2a;
    float boa   = pb / pa;
    float nbl   = -1.4426950408889634f / pb;   // exp(-pet/b)=exp2(pet*this)
    float i1d   = 1.0f / (1.0f + pd);

    float S = 50.0f, G = 10.0f;
    float4* ps4 = sg4 + gid;                   // advances SGW float4 per pair

    float2 Ra[8], Rb[8], V0[8], V1[8], V2[8];
    DSLD(Ra, 0)
    DSLD(Rb, 1)
    CONV(V0, Ra)

    for (int g = 0; g < 15; ++g) {             // chunks 6g .. 6g+5
        const int c0 = 6 * g;
        DSLD(Ra, c0 + 2)  CONV(V1, Rb)  CONS(V0)
        DSLD(Rb, c0 + 3)  CONV(V2, Ra)  CONS(V1)
        DSLD(Ra, c0 + 4)  CONV(V0, Rb)  CONS(V2)
        DSLD(Rb, c0 + 5)  CONV(V1, Ra)  CONS(V0)
        DSLD(Ra, c0 + 6)  CONV(V2, Rb)  CONS(V1)
        DSLD(Rb, c0 + 7)  CONV(V0, Ra)  CONS(V2)
    }
    CONV(V1, Rb)   CONS(V0)                    // steps 720..727
    STEPP(V1[0], V1[1])                        // steps 728,729 (pair 364)
}

// ===========================================================================
// 8-lane butterfly reduction (groups of 8 consecutive lanes = one basin).
// ===========================================================================
template <int CTRL>
__device__ __forceinline__ float dpp_mov(float x) {
    int xi = __builtin_bit_cast(int, x);
    int r  = __builtin_amdgcn_update_dpp(0, xi, CTRL, 0xF, 0xF, true);
    return __builtin_bit_cast(float, r);
}
__device__ __forceinline__ float sum8(float v) {
    v += dpp_mov<0xB1>(v);    // xor 1
    v += dpp_mov<0x4E>(v);    // xor 2
    v += dpp_mov<0x141>(v);   // xor 4 within 8-group
    return v;
}

// ===========================================================================
// PASS B: t-parallel finalize, STORE-FREE row loop (R10).
// Block = 256 thr = 32 basins x 8 members; grid (15, 32).
// 8-deep pair pipeline over 32 pairs (64 rows incl 14 halo); S[t-1] carried
// in-register; qs/qg + ch3..5 sums staged in LDS; post-barrier phase does
// the 15-tap conv (ch0..2) and the coalesced ch3..5 writes.
// ===========================================================================
#define ROW(SN, GN, XV, TTE, RE)                                               \
  {                                                                            \
    const int tt = (TTE); const int r = (RE);                                  \
    const bool tval = (tt >= 0) && (tt < T_STEPS);                             \
    float qs = 0.f, qg = 0.f, aet = 0.f, sX = 0.f, gX = 0.f;                   \
    if (tval) {                                                                \
      float sn  = (SN);                                                        \
      float spv = (tt == 0) ? 50.0f : Sprev;                                   \
      float y   = sn * __builtin_amdgcn_exp2f((XV).y * e2s);                   \
      float avail = ((XV).x + spv) - y;                                        \
      qs = omc * avail; qg = dm * (GN); aet = y - sn; sX = sn; gX = (GN);      \
      Sprev = sn;                                                              \
    }                                                                          \
    qs = sum8(qs); qg = sum8(qg);                                              \
    if (m == 0) { qsh[r][lb] = qs; qgh[r][lb] = qg; }                          \
    if (r >= 14 && tval) {                                                     \
      float a_s = sum8(aet), s_s = sum8(sX), g_s = sum8(gX);                   \
      if (m == 0) {                                                            \
        ash[r - 14][lb] = a_s; ssh[r - 14][lb] = s_s; gsh[r - 14][lb] = g_s;   \
      }                                                                        \
    }                                                                          \
  }

__global__ __launch_bounds__(256) void finalize(const float* __restrict__ x,
                                                const float* __restrict__ raw,
                                                const float4* __restrict__ sg4,
                                                float* __restrict__ out) {
    __shared__ float qsh[TT + 14][BBLK + 1];
    __shared__ float qgh[TT + 14][BBLK + 1];
    __shared__ float ash[TT][BBLK + 1];
    __shared__ float ssh[TT][BBLK + 1];
    __shared__ float gsh[TT][BBLK + 1];

    const int tid   = threadIdx.x;
    const int lb    = tid >> 3;          // local basin 0..31
    const int m     = tid & 7;
    const int tbase = blockIdx.x * TT;   // even
    const int b0    = blockIdx.y * BBLK;
    const int b     = b0 + lb;
    const bool bval = b < NB;
    const int bc    = bval ? b : (NB - 1);      // clamped for loads
    const int lane  = bc * 8 + m;               // 0..7999

    const float* rp = raw + bc * 34;
    float pbm = rp[8 + m] * 450.0f + 50.0f;
    float e2s = 1.4426950408889634f / pbm;      // y = sn * exp2(pet * e2s)
    float omc = 1.0f - rp[16 + m];
    float dm  = rp[24 + m] * 0.89f + 0.01f;

    const float2* __restrict__ xf = (const float2*)x;
    const int Pbase = (tbase - 14) >> 1;        // pair idx of row 0 (may be <0)

    // ---- 8-deep pair pipeline: 32 pairs = 64 rows ------------------------
    float4 sgb[8];
    float2 pv0[8], pv1[8];
#pragma unroll
    for (int d = 0; d < 8; ++d) {
        int P = Pbase + d; P = P < 0 ? 0 : (P > NPAIR - 1 ? NPAIR - 1 : P);
        sgb[d] = sg4[(size_t)P * SGW + lane];
        int t0 = tbase - 14 + 2 * d;
        int tc0 = t0 < 0 ? 0 : (t0 > T_STEPS - 1 ? T_STEPS - 1 : t0);
        int tc1 = t0 + 1 < 0 ? 0 : (t0 + 1 > T_STEPS - 1 ? T_STEPS - 1 : t0 + 1);
        pv0[d] = xf[tc0 * NB + bc];
        pv1[d] = xf[tc1 * NB + bc];
    }
    float Sprev = (tbase > 0)
        ? sg4[(size_t)((tbase - 16) >> 1) * SGW + lane].z   // Sn at t=tbase-15
        : 50.0f;

    for (int pp = 0; pp < 32; pp += 8) {
#pragma unroll
        for (int d = 0; d < 8; ++d) {
            const int p = pp + d;
            float4 sv = sgb[d];
            float2 x0 = pv0[d], x1 = pv1[d];
            {   // issue pair p+8 loads (clamped; tail loads harmless)
                int Pn = Pbase + p + 8;
                Pn = Pn < 0 ? 0 : (Pn > NPAIR - 1 ? NPAIR - 1 : Pn);
                sgb[d] = sg4[(size_t)Pn * SGW + lane];
                int tn = tbase - 14 + 2 * (p + 8);
                int tc0 = tn < 0 ? 0 : (tn > T_STEPS - 1 ? T_STEPS - 1 : tn);
                int tc1 = tn + 1 < 0 ? 0 : (tn + 1 > T_STEPS - 1 ? T_STEPS - 1 : tn + 1);
                pv0[d] = xf[tc0 * NB + bc];
                pv1[d] = xf[tc1 * NB + bc];
            }
            ROW(sv.x, sv.y, x0, tbase - 14 + 2 * p,     2 * p)
            ROW(sv.z, sv.w, x1, tbase - 14 + 2 * p + 1, 2 * p + 1)
        }
    }
    __syncthreads();

    // ---- ch3..5 write phase: flat-indexed, no loads behind it ------------
#pragma unroll
    for (int it = 0; it < (TT * 96 + 255) / 256; ++it) {    // 19
        int idx = it * 256 + tid;
        if (idx < TT * 96) {
            int tl = idx / 96;
            int j  = idx - tl * 96;
            int bb = j / 3;
            int ch = j - bb * 3;
            int t  = tbase + tl;
            int b3 = b0 + bb;
            if (t < T_STEPS && b3 < NB) {
                float v = (ch == 0) ? ash[tl][bb]
                        : (ch == 1) ? ssh[tl][bb] : gsh[tl][bb];
                out[((size_t)t * NB + b3) * 6 + 3 + ch] = v * 0.125f;
            }
        }
    }

    // ---- conv phase: threads = (t-slot 0..7) x (basin 0..31) -------------
    const int bl2 = tid & 31;
    const int tl0 = tid >> 5;                   // 0..7
    const int b2  = b0 + bl2;
    if (b2 >= NB) return;

    const float* rp2 = raw + b2 * 34;
    float ra = rp2[32] * 2.9f;
    float rb = rp2[33] * 6.5f;
    float aa = fmaxf(ra, 0.0f) + 0.1f;
    float th = fmaxf(rb, 0.0f) + 0.5f;
    float inv_th = 1.0f / th;
    float am1 = aa - 1.0f;
    float w[LENF];
    float sw = 0.0f;
#pragma unroll
    for (int k = 0; k < LENF; ++k) {
        float tk = (float)k + 0.5f;
        w[k] = __expf(am1 * __logf(tk) - tk * inv_th);
        sw += w[k];
    }
    float invs = 0.125f / sw;      // UH normalization x ensemble mean
#pragma unroll
    for (int k = 0; k < LENF; ++k) w[k] *= invs;

#pragma unroll
    for (int it = 0; it < 7; ++it) {
        int tl = tl0 + it * 8;                  // 0..55
        int t  = tbase + tl;
        if (tl < TT && t < T_STEPS) {
            float ys = 0.0f, yg = 0.0f;
#pragma unroll
            for (int k = 0; k < LENF; ++k) {
                ys = fmaf(qsh[tl + 14 - k][bl2], w[k], ys);
                yg = fmaf(qgh[tl + 14 - k][bl2], w[k], yg);
            }
            float* o = out + ((size_t)t * NB + b2) * 6;
            o[0] = ys + yg;
            o[1] = ys;
            o[2] = yg;
        }
    }
}

// ===========================================================================
// FALLBACK (ws too small for the 47MB plane): R8's proven path.
// ===========================================================================
#define STEPF(CURV)                                                            \
  {                                                                            \
    float pcp = (CURV).x, pet = (CURV).y;                                      \
    float W     = pcp + S;                                                     \
    float term  = fmaf(W, inv2a, pb2a);                                        \
    float disc  = fmaf(term, term, -(W * boa));                                \
    float r     = __builtin_amdgcn_sqrtf(fmaxf(disc, NEARZ));                  \
    float Y     = term - r;                                                    \
    float e     = __builtin_amdgcn_exp2f(pet * ninvbl2);                       \
    float Sn    = Y * e;                                                       \
    float AET   = Y - Sn;                                                      \
    float avail = W - Y;                                                       \
    float Qs    = omc * avail;                                                 \
    float Gn    = fmaf(pc, avail, G) * inv1pd;                                 \
    float Qg    = pd * Gn;                                                     \
    S = Sn; G = Gn;                                                            \
    float qs_s = sum8(Qs);                                                     \
    float qg_s = sum8(Qg);                                                     \
    float ae_s = sum8(AET);                                                    \
    float s_s  = sum8(Sn);                                                     \
    float g_s  = sum8(Gn);                                                     \
    float v = qs_s;                                                            \
    v = (m == 1) ? qg_s : v;                                                   \
    v = (m == 2) ? ae_s : v;                                                   \
    v = (m == 3) ? s_s  : v;                                                   \
    v = (m >= 4) ? g_s  : v;                                                   \
    *optr = v * 0.125f;                                                        \
    optr += incr;                                                              \
  }

__global__ __launch_bounds__(64, 1) void scan_fb(const float* __restrict__ x,
                                                 const float* __restrict__ raw,
                                                 float* __restrict__ out,
                                                 float* __restrict__ qs_ws,
                                                 float* __restrict__ qg_ws,
                                                 float* __restrict__ dummy) {
    const int L  = threadIdx.x;
    const int lb = L >> 3;
    const int m  = L & 7;
    const int b  = blockIdx.x * 8 + lb;

    const float* rp = raw + b * 34;
    float pa = rp[0 * 8 + m] * 0.9f + 0.1f;
    float pb = rp[1 * 8 + m] * 450.0f + 50.0f;
    float pc = rp[2 * 8 + m];
    float pd = rp[3 * 8 + m] * 0.89f + 0.01f;
    float inv2a   = 1.0f / (2.0f * pa);
    float pb2a    = pb * inv2a;
    float boa     = pb / pa;
    float ninvbl2 = -1.4426950408889634f / pb;
    float omc     = 1.0f - pc;
    float inv1pd  = 1.0f / (1.0f + pd);

    float* optr;
    long long incr;
    if      (m == 0) { optr = qs_ws + b;                      incr = NB;     }
    else if (m == 1) { optr = qg_ws + b;                      incr = NB;     }
    else if (m <= 4) { optr = out + (long long)b * 6 + m + 1; incr = NB * 6; }
    else             { optr = dummy + (blockIdx.x * 64 + L);  incr = 0;      }

    float S = 50.0f, G = 10.0f;
    const float2* __restrict__ xf = (const float2*)x;

    float2 A[10], B[10], C[10];
#pragma unroll
    for (int j = 0; j < 10; ++j) A[j] = xf[j * NB + b];
#pragma unroll
    for (int j = 0; j < 10; ++j) B[j] = xf[(10 + j) * NB + b];

    for (int cg = 0; cg < 24; ++cg) {
        const int c0 = 3 * cg;
#pragma unroll
        for (int j = 0; j < 10; ++j) C[j] = xf[((c0 + 2) * 10 + j) * NB + b];
        __builtin_amdgcn_sched_barrier(0);
#pragma unroll
        for (int j = 0; j < 10; ++j) STEPF(A[j]);
#pragma unroll
        for (int j = 0; j < 10; ++j) A[j] = xf[((c0 + 3) * 10 + j) * NB + b];
        __builtin_amdgcn_sched_barrier(0);
#pragma unroll
        for (int j = 0; j < 10; ++j) STEPF(B[j]);
#pragma unroll
        for (int j = 0; j < 10; ++j) {
            int t = (c0 + 4) * 10 + j;
            t = t < T_STEPS ? t : (T_STEPS - 1);
            B[j] = xf[t * NB + b];
        }
        __builtin_amdgcn_sched_barrier(0);
#pragma unroll
        for (int j = 0; j < 10; ++j) STEPF(C[j]);
    }
#pragma unroll
    for (int j = 0; j < 10; ++j) STEPF(A[j]);
}

__global__ __launch_bounds__(256) void uh_fb(const float* __restrict__ raw,
                                             float* __restrict__ uh) {
    int b = blockIdx.x * 256 + threadIdx.x;
    if (b >= NB) return;
    float ra = raw[b * 34 + 32] * 2.9f;
    float rb = raw[b * 34 + 33] * 6.5f;
    float aa = fmaxf(ra, 0.0f) + 0.1f;
    float th = fmaxf(rb, 0.0f) + 0.5f;
    float inv_th = 1.0f / th;
    float am1 = aa - 1.0f;
    float w[LENF];
    float s = 0.0f;
#pragma unroll
    for (int k = 0; k < LENF; ++k) {
        float t = (float)k + 0.5f;
        w[k] = __expf(am1 * __logf(t) - t * inv_th);
        s += w[k];
    }
    float invs = 1.0f / s;
#pragma unroll
    for (int k = 0; k < LENF; ++k) uh[k * NB + b] = w[k] * invs;
}

__global__ __launch_bounds__(256) void conv_fb(const float* __restrict__ qs_ws,
                                               const float* __restrict__ qg_ws,
                                               const float* __restrict__ uh,
                                               float* __restrict__ out) {
    int b = blockIdx.x * 256 + threadIdx.x;
    int t = blockIdx.y;
    if (b >= NB) return;
    float ys = 0.0f, yg = 0.0f;
    int kmax = t < (LENF - 1) ? t : (LENF - 1);
    for (int k = 0; k <= kmax; ++k) {
        float w = uh[k * NB + b];
        ys = fmaf(qs_ws[(t - k) * NB + b], w, ys);
        yg = fmaf(qg_ws[(t - k) * NB + b], w, yg);
    }
    float* o = out + (t * NB + b) * 6;
    o[0] = ys + yg;
    o[1] = ys;
    o[2] = yg;
}

// ===========================================================================
extern "C" void kernel_launch(void* const* d_in, const int* in_sizes, int n_in,
                              void* d_out, int out_size, void* d_ws, size_t ws_size,
                              hipStream_t stream) {
    const float* x   = (const float*)d_in[0];   // (T,B,2) fp32
    const float* raw = (const float*)d_in[1];   // (B,34)  fp32
    float* out = (float*)d_out;                 // (T,B,6) fp32

    const size_t need = (size_t)NPAIR * SGW * sizeof(float4);  // 46.7 MB
    if (ws_size >= need) {
        float4* sg4 = (float4*)d_ws;
        scan_state<<<dim3(SGW / 64), dim3(64),  0, stream>>>(x, raw, sg4);
        finalize  <<<dim3((T_STEPS + TT - 1) / TT, (NB + BBLK - 1) / BBLK),
                     dim3(256), 0, stream>>>(x, raw, sg4, out);
    } else {
        float* qs = (float*)d_ws;
        float* qg = qs + (size_t)T_STEPS * NB;
        float* uh = qg + (size_t)T_STEPS * NB;
        float* dm = uh + (size_t)LENF * NB;
        uh_fb  <<<dim3((NB + 255) / 256),          dim3(256), 0, stream>>>(raw, uh);
        scan_fb<<<dim3(NB / 8),                    dim3(64),  0, stream>>>(x, raw, out, qs, qg, dm);
        conv_fb<<<dim3((NB + 255) / 256, T_STEPS), dim3(256), 0, stream>>>(qs, qg, uh, out);
    }
}

// Round 11
// 113.307 us; speedup vs baseline: 1.0158x; 1.0158x over previous
//
#include <hip/hip_runtime.h>
#include <math.h>

#define T_STEPS 730
#define NB      1000
#define LENF    15
#define NEARZ   1e-5f
#define SGW     8000           // plane width: 1000 basins x 8 members
#define NPAIR   365            // 730/2 (Sn,Gn) pairs per lane
#define TT      50             // finalize: t-rows per block (even!)
#define BBLK    32             // finalize: basins per block

// ===========================================================================
// R11 = R9 (best, 113.0us) with a GENUINE scan slot cut.  R9/R7 model
// reconciliation: R9's CONV make_float2 forced a p-copy (Rb overwritten by
// the next DSLD before CONS in program order) -> R9's net slot change was
// ~-3%, not -8%; both R7 (x2.1 slots -> x2.1 time) and R9 (null) fit the
// slot law.  Real cut here: LDS source needs only 1-chunk lookahead (~120cy),
// so the phase becomes DSLD(next) -> CONV(E,cur) -> CONS(cur,E): consume
// happens BEFORE the same buffer reloads -> p read in place from R[j].x,
// E[] holds only exp2.  ~15.5 -> ~13.5 slots/step; 2 buffers + E (VGPR down).
// Finalize: R9's byte-identical (R10's store-free variant nulled, reverted).
// ===========================================================================

// ---- PASS A ---------------------------------------------------------------
#define DSLD(R, CI)                                                            \
  _Pragma("unroll")                                                            \
  for (int j = 0; j < 8; ++j) R[j] = xs[((CI) * 8 + j) * 8 + bl];              \
  __builtin_amdgcn_sched_barrier(0);

// E[j] = exp2(pet*nbl) only; p stays in R (consumed before R reloads)
#define CONV(E, R)                                                             \
  _Pragma("unroll")                                                            \
  for (int j = 0; j < 8; ++j) E[j] = __builtin_amdgcn_exp2f(R[j].y * nbl);

// two chained steps, one float4 store (.xy = even step, .zw = odd step)
#define STEPP(P0, E0, P1, E1)                                                  \
  {                                                                            \
    float W0  = (P0) + S;                                                      \
    float t0  = fmaf(W0, inv2a, pb2a);                                         \
    float d0  = fmaf(t0, t0, -(W0 * boa));                                     \
    float r0  = __builtin_amdgcn_sqrtf(fmaxf(d0, NEARZ));                      \
    float Y0  = t0 - r0;                                                       \
    float Sn0 = Y0 * (E0);                                                     \
    float av0 = W0 - Y0;                                                       \
    float Gn0 = fmaf(pc, av0, G) * i1d;                                        \
    float W1  = (P1) + Sn0;                                                    \
    float t1  = fmaf(W1, inv2a, pb2a);                                         \
    float d1  = fmaf(t1, t1, -(W1 * boa));                                     \
    float r1  = __builtin_amdgcn_sqrtf(fmaxf(d1, NEARZ));                      \
    float Y1  = t1 - r1;                                                       \
    float Sn1 = Y1 * (E1);                                                     \
    float av1 = W1 - Y1;                                                       \
    G = fmaf(pc, av1, Gn0) * i1d;                                              \
    S = Sn1;                                                                   \
    *ps4 = make_float4(Sn0, Gn0, Sn1, G);                                      \
    ps4 += SGW;                                                                \
  }

#define CONS(R, E) STEPP(R[0].x, E[0], R[1].x, E[1])                           \
                   STEPP(R[2].x, E[2], R[3].x, E[3])                           \
                   STEPP(R[4].x, E[4], R[5].x, E[5])                           \
                   STEPP(R[6].x, E[6], R[7].x, E[7])

__global__ __launch_bounds__(64, 1) void scan_state(const float* __restrict__ x,
                                                    const float* __restrict__ raw,
                                                    float4* __restrict__ sg4) {
    __shared__ float4 xs4[2944];               // 736 rows x 8 basins x float2
    const float2* xs = (const float2*)xs4;

    const int L   = threadIdx.x;
    const int gid = blockIdx.x * 64 + L;       // 0..7999 (grid=125)
    const int b   = gid >> 3;
    const int m   = gid & 7;
    const int bl  = L >> 3;                    // basin-local 0..7

    // ---- one-time cooperative x -> LDS stage (R3-proven) ------------------
    {
        float4 tmp[46];
#pragma unroll
        for (int ch = 0; ch < 46; ++ch) {
            int idx = ch * 64 + L;             // 0..2943
            int row = idx >> 2;                // t row 0..735
            row = row < T_STEPS ? row : (T_STEPS - 1);
            tmp[ch] = *(const float4*)((const char*)x + (size_t)row * (NB * 8)
                                       + (size_t)(blockIdx.x * 64)
                                       + (size_t)(idx & 3) * 16);
        }
#pragma unroll
        for (int ch = 0; ch < 46; ++ch) xs4[ch * 64 + L] = tmp[ch];
    }
    __syncthreads();

    // raw layout (B,34) = [a(8), b(8), c(8), d(8), ra, rb]
    const float* rp = raw + b * 34;
    float pa = rp[0 * 8 + m] * 0.9f + 0.1f;
    float pb = rp[1 * 8 + m] * 450.0f + 50.0f;
    float pc = rp[2 * 8 + m];
    float pd = rp[3 * 8 + m] * 0.89f + 0.01f;

    float inv2a = 1.0f / (2.0f * pa);
    float pb2a  = pb * inv2a;
    float boa   = pb / pa;
    float nbl   = -1.4426950408889634f / pb;   // exp(-pet/b)=exp2(pet*this)
    float i1d   = 1.0f / (1.0f + pd);

    float S = 50.0f, G = 10.0f;
    float4* ps4 = sg4 + gid;                   // advances SGW float4 per pair

    // 2-buffer, consume-before-reload: DSLD(next); CONV(E,cur); CONS(cur,E)
    float2 Ra[8], Rb[8];
    float  E[8];
    DSLD(Ra, 0)

    for (int g = 0; g < 45; ++g) {             // chunks 0..89 (90 chunks)
        const int c0 = 2 * g;
        DSLD(Rb, c0 + 1)  CONV(E, Ra)  CONS(Ra, E)
        DSLD(Ra, c0 + 2)  CONV(E, Rb)  CONS(Rb, E)
    }
    // Ra holds chunk 90 (steps 720..727); chunk 91 rows 728..735 (clamped)
    DSLD(Rb, 91)  CONV(E, Ra)  CONS(Ra, E)
    CONV(E, Rb)
    STEPP(Rb[0].x, E[0], Rb[1].x, E[1])        // steps 728,729 (pair 364)
}

// ===========================================================================
// 8-lane butterfly reduction (groups of 8 consecutive lanes = one basin).
// ===========================================================================
template <int CTRL>
__device__ __forceinline__ float dpp_mov(float x) {
    int xi = __builtin_bit_cast(int, x);
    int r  = __builtin_amdgcn_update_dpp(0, xi, CTRL, 0xF, 0xF, true);
    return __builtin_bit_cast(float, r);
}
__device__ __forceinline__ float sum8(float v) {
    v += dpp_mov<0xB1>(v);    // xor 1
    v += dpp_mov<0x4E>(v);    // xor 2
    v += dpp_mov<0x141>(v);   // xor 4 within 8-group
    return v;
}

// ===========================================================================
// PASS B: t-parallel finalize on the PAIRED plane (R9's proven kernel,
// byte-identical).  Block = 256 thr = 32 basins x 8 members; grid (15, 32).
// ===========================================================================
#define ROW(SN, GN, XV, TTE, RE)                                               \
  {                                                                            \
    const int tt = (TTE); const int r = (RE);                                  \
    const bool tval = (tt >= 0) && (tt < T_STEPS);                             \
    float qs = 0.f, qg = 0.f, aet = 0.f, sX = 0.f, gX = 0.f;                   \
    if (tval) {                                                                \
      float sn  = (SN);                                                        \
      float spv = (tt == 0) ? 50.0f : Sprev;                                   \
      float y   = sn * __builtin_amdgcn_exp2f((XV).y * e2s);                   \
      float avail = ((XV).x + spv) - y;                                        \
      qs = omc * avail; qg = dm * (GN); aet = y - sn; sX = sn; gX = (GN);      \
      Sprev = sn;                                                              \
    }                                                                          \
    qs = sum8(qs); qg = sum8(qg);                                              \
    if (m == 0) { qsh[r][lb] = qs; qgh[r][lb] = qg; }                          \
    if (r >= 14 && tval) {                                                     \
      float a_s = sum8(aet), s_s = sum8(sX), g_s = sum8(gX);                   \
      if (bval && m < 3) {                                                     \
        float v = (m == 0) ? a_s : ((m == 1) ? s_s : g_s);                     \
        out[((size_t)tt * NB + b) * 6 + 3 + m] = v * 0.125f;                   \
      }                                                                        \
    }                                                                          \
  }

__global__ __launch_bounds__(256) void finalize(const float* __restrict__ x,
                                                const float* __restrict__ raw,
                                                const float4* __restrict__ sg4,
                                                float* __restrict__ out) {
    __shared__ float qsh[TT + 14][BBLK + 1];
    __shared__ float qgh[TT + 14][BBLK + 1];

    const int tid   = threadIdx.x;
    const int lb    = tid >> 3;          // local basin 0..31
    const int m     = tid & 7;
    const int tbase = blockIdx.x * TT;   // even
    const int b0    = blockIdx.y * BBLK;
    const int b     = b0 + lb;
    const bool bval = b < NB;
    const int bc    = bval ? b : (NB - 1);      // clamped for loads
    const int lane  = bc * 8 + m;               // 0..7999

    const float* rp = raw + bc * 34;
    float pbm = rp[8 + m] * 450.0f + 50.0f;
    float e2s = 1.4426950408889634f / pbm;      // y = sn * exp2(pet * e2s)
    float omc = 1.0f - rp[16 + m];
    float dm  = rp[24 + m] * 0.89f + 0.01f;

    const float2* __restrict__ xf = (const float2*)x;
    const int Pbase = (tbase - 14) >> 1;        // pair idx of row 0 (may be <0)

    // ---- 4-deep pair pipeline: 32 pairs = 64 rows ------------------------
    float4 sgb[4];
    float2 pv0[4], pv1[4];
#pragma unroll
    for (int d = 0; d < 4; ++d) {
        int P = Pbase + d; P = P < 0 ? 0 : (P > NPAIR - 1 ? NPAIR - 1 : P);
        sgb[d] = sg4[(size_t)P * SGW + lane];
        int t0 = tbase - 14 + 2 * d;
        int tc0 = t0 < 0 ? 0 : (t0 > T_STEPS - 1 ? T_STEPS - 1 : t0);
        int tc1 = t0 + 1 < 0 ? 0 : (t0 + 1 > T_STEPS - 1 ? T_STEPS - 1 : t0 + 1);
        pv0[d] = xf[tc0 * NB + bc];
        pv1[d] = xf[tc1 * NB + bc];
    }
    float Sprev = (tbase > 0)
        ? sg4[(size_t)((tbase - 16) >> 1) * SGW + lane].z   // Sn at t=tbase-15
        : 50.0f;

    for (int pp = 0; pp < 32; pp += 4) {
#pragma unroll
        for (int d = 0; d < 4; ++d) {
            const int p = pp + d;
            float4 sv = sgb[d];
            float2 x0 = pv0[d], x1 = pv1[d];
            {   // issue pair p+4 loads (clamped; tail loads harmless)
                int Pn = Pbase + p + 4;
                Pn = Pn < 0 ? 0 : (Pn > NPAIR - 1 ? NPAIR - 1 : Pn);
                sgb[d] = sg4[(size_t)Pn * SGW + lane];
                int tn = tbase - 14 + 2 * (p + 4);
                int tc0 = tn < 0 ? 0 : (tn > T_STEPS - 1 ? T_STEPS - 1 : tn);
                int tc1 = tn + 1 < 0 ? 0 : (tn + 1 > T_STEPS - 1 ? T_STEPS - 1 : tn + 1);
                pv0[d] = xf[tc0 * NB + bc];
                pv1[d] = xf[tc1 * NB + bc];
            }
            ROW(sv.x, sv.y, x0, tbase - 14 + 2 * p,     2 * p)
            ROW(sv.z, sv.w, x1, tbase - 14 + 2 * p + 1, 2 * p + 1)
        }
    }
    __syncthreads();

    // ---- conv phase: threads = (t-slot 0..7) x (basin 0..31) -------------
    const int bl2 = tid & 31;
    const int tl0 = tid >> 5;                   // 0..7
    const int b2  = b0 + bl2;
    if (b2 >= NB) return;

    const float* rp2 = raw + b2 * 34;
    float ra = rp2[32] * 2.9f;
    float rb = rp2[33] * 6.5f;
    float aa = fmaxf(ra, 0.0f) + 0.1f;
    float th = fmaxf(rb, 0.0f) + 0.5f;
    float inv_th = 1.0f / th;
    float am1 = aa - 1.0f;
    float w[LENF];
    float sw = 0.0f;
#pragma unroll
    for (int k = 0; k < LENF; ++k) {
        float tk = (float)k + 0.5f;
        w[k] = __expf(am1 * __logf(tk) - tk * inv_th);
        sw += w[k];
    }
    float invs = 0.125f / sw;      // UH normalization x ensemble mean
#pragma unroll
    for (int k = 0; k < LENF; ++k) w[k] *= invs;

#pragma unroll
    for (int it = 0; it < 7; ++it) {
        int tl = tl0 + it * 8;                  // 0..55
        int t  = tbase + tl;
        if (tl < TT && t < T_STEPS) {
            float ys = 0.0f, yg = 0.0f;
#pragma unroll
            for (int k = 0; k < LENF; ++k) {
                ys = fmaf(qsh[tl + 14 - k][bl2], w[k], ys);
                yg = fmaf(qgh[tl + 14 - k][bl2], w[k], yg);
            }
            float* o = out + ((size_t)t * NB + b2) * 6;
            o[0] = ys + yg;
            o[1] = ys;
            o[2] = yg;
        }
    }
}

// ===========================================================================
// FALLBACK (ws too small for the 47MB plane): R8's proven path.
// ===========================================================================
#define STEPF(CURV)                                                            \
  {                                                                            \
    float pcp = (CURV).x, pet = (CURV).y;                                      \
    float W     = pcp + S;                                                     \
    float term  = fmaf(W, inv2a, pb2a);                                        \
    float disc  = fmaf(term, term, -(W * boa));                                \
    float r     = __builtin_amdgcn_sqrtf(fmaxf(disc, NEARZ));                  \
    float Y     = term - r;                                                    \
    float e     = __builtin_amdgcn_exp2f(pet * ninvbl2);                       \
    float Sn    = Y * e;                                                       \
    float AET   = Y - Sn;                                                      \
    float avail = W - Y;                                                       \
    float Qs    = omc * avail;                                                 \
    float Gn    = fmaf(pc, avail, G) * inv1pd;                                 \
    float Qg    = pd * Gn;                                                     \
    S = Sn; G = Gn;                                                            \
    float qs_s = sum8(Qs);                                                     \
    float qg_s = sum8(Qg);                                                     \
    float ae_s = sum8(AET);                                                    \
    float s_s  = sum8(Sn);                                                     \
    float g_s  = sum8(Gn);                                                     \
    float v = qs_s;                                                            \
    v = (m == 1) ? qg_s : v;                                                   \
    v = (m == 2) ? ae_s : v;                                                   \
    v = (m == 3) ? s_s  : v;                                                   \
    v = (m >= 4) ? g_s  : v;                                                   \
    *optr = v * 0.125f;                                                        \
    optr += incr;                                                              \
  }

__global__ __launch_bounds__(64, 1) void scan_fb(const float* __restrict__ x,
                                                 const float* __restrict__ raw,
                                                 float* __restrict__ out,
                                                 float* __restrict__ qs_ws,
                                                 float* __restrict__ qg_ws,
                                                 float* __restrict__ dummy) {
    const int L  = threadIdx.x;
    const int lb = L >> 3;
    const int m  = L & 7;
    const int b  = blockIdx.x * 8 + lb;

    const float* rp = raw + b * 34;
    float pa = rp[0 * 8 + m] * 0.9f + 0.1f;
    float pb = rp[1 * 8 + m] * 450.0f + 50.0f;
    float pc = rp[2 * 8 + m];
    float pd = rp[3 * 8 + m] * 0.89f + 0.01f;
    float inv2a   = 1.0f / (2.0f * pa);
    float pb2a    = pb * inv2a;
    float boa     = pb / pa;
    float ninvbl2 = -1.4426950408889634f / pb;
    float omc     = 1.0f - pc;
    float inv1pd  = 1.0f / (1.0f + pd);

    float* optr;
    long long incr;
    if      (m == 0) { optr = qs_ws + b;                      incr = NB;     }
    else if (m == 1) { optr = qg_ws + b;                      incr = NB;     }
    else if (m <= 4) { optr = out + (long long)b * 6 + m + 1; incr = NB * 6; }
    else             { optr = dummy + (blockIdx.x * 64 + L);  incr = 0;      }

    float S = 50.0f, G = 10.0f;
    const float2* __restrict__ xf = (const float2*)x;

    float2 A[10], B[10], C[10];
#pragma unroll
    for (int j = 0; j < 10; ++j) A[j] = xf[j * NB + b];
#pragma unroll
    for (int j = 0; j < 10; ++j) B[j] = xf[(10 + j) * NB + b];

    for (int cg = 0; cg < 24; ++cg) {
        const int c0 = 3 * cg;
#pragma unroll
        for (int j = 0; j < 10; ++j) C[j] = xf[((c0 + 2) * 10 + j) * NB + b];
        __builtin_amdgcn_sched_barrier(0);
#pragma unroll
        for (int j = 0; j < 10; ++j) STEPF(A[j]);
#pragma unroll
        for (int j = 0; j < 10; ++j) A[j] = xf[((c0 + 3) * 10 + j) * NB + b];
        __builtin_amdgcn_sched_barrier(0);
#pragma unroll
        for (int j = 0; j < 10; ++j) STEPF(B[j]);
#pragma unroll
        for (int j = 0; j < 10; ++j) {
            int t = (c0 + 4) * 10 + j;
            t = t < T_STEPS ? t : (T_STEPS - 1);
            B[j] = xf[t * NB + b];
        }
        __builtin_amdgcn_sched_barrier(0);
#pragma unroll
        for (int j = 0; j < 10; ++j) STEPF(C[j]);
    }
#pragma unroll
    for (int j = 0; j < 10; ++j) STEPF(A[j]);
}

__global__ __launch_bounds__(256) void uh_fb(const float* __restrict__ raw,
                                             float* __restrict__ uh) {
    int b = blockIdx.x * 256 + threadIdx.x;
    if (b >= NB) return;
    float ra = raw[b * 34 + 32] * 2.9f;
    float rb = raw[b * 34 + 33] * 6.5f;
    float aa = fmaxf(ra, 0.0f) + 0.1f;
    float th = fmaxf(rb, 0.0f) + 0.5f;
    float inv_th = 1.0f / th;
    float am1 = aa - 1.0f;
    float w[LENF];
    float s = 0.0f;
#pragma unroll
    for (int k = 0; k < LENF; ++k) {
        float t = (float)k + 0.5f;
        w[k] = __expf(am1 * __logf(t) - t * inv_th);
        s += w[k];
    }
    float invs = 1.0f / s;
#pragma unroll
    for (int k = 0; k < LENF; ++k) uh[k * NB + b] = w[k] * invs;
}

__global__ __launch_bounds__(256) void conv_fb(const float* __restrict__ qs_ws,
                                               const float* __restrict__ qg_ws,
                                               const float* __restrict__ uh,
                                               float* __restrict__ out) {
    int b = blockIdx.x * 256 + threadIdx.x;
    int t = blockIdx.y;
    if (b >= NB) return;
    float ys = 0.0f, yg = 0.0f;
    int kmax = t < (LENF - 1) ? t : (LENF - 1);
    for (int k = 0; k <= kmax; ++k) {
        float w = uh[k * NB + b];
        ys = fmaf(qs_ws[(t - k) * NB + b], w, ys);
        yg = fmaf(qg_ws[(t - k) * NB + b], w, yg);
    }
    float* o = out + (t * NB + b) * 6;
    o[0] = ys + yg;
    o[1] = ys;
    o[2] = yg;
}

// ===========================================================================
extern "C" void kernel_launch(void* const* d_in, const int* in_sizes, int n_in,
                              void* d_out, int out_size, void* d_ws, size_t ws_size,
                              hipStream_t stream) {
    const float* x   = (const float*)d_in[0];   // (T,B,2) fp32
    const float* raw = (const float*)d_in[1];   // (B,34)  fp32
    float* out = (float*)d_out;                 // (T,B,6) fp32

    const size_t need = (size_t)NPAIR * SGW * sizeof(float4);  // 46.7 MB
    if (ws_size >= need) {
        float4* sg4 = (float4*)d_ws;
        scan_state<<<dim3(SGW / 64), dim3(64),  0, stream>>>(x, raw, sg4);
        finalize  <<<dim3((T_STEPS + TT - 1) / TT, (NB + BBLK - 1) / BBLK),
                     dim3(256), 0, stream>>>(x, raw, sg4, out);
    } else {
        float* qs = (float*)d_ws;
        float* qg = qs + (size_t)T_STEPS * NB;
        float* uh = qg + (size_t)T_STEPS * NB;
        float* dm = uh + (size_t)LENF * NB;
        uh_fb  <<<dim3((NB + 255) / 256),          dim3(256), 0, stream>>>(raw, uh);
        scan_fb<<<dim3(NB / 8),                    dim3(64),  0, stream>>>(x, raw, out, qs, qg, dm);
        conv_fb<<<dim3((NB + 255) / 256, T_STEPS), dim3(256), 0, stream>>>(qs, qg, uh, out);
    }
}